// Round 20
// baseline (110.205 us; speedup 1.0000x reference)
//
#include <hip/hip_runtime.h>
#include <hip/hip_bf16.h>
#include <cstdint>
#include <cstddef>

#define E_DIM 1024
#define PD 64            // proj dim
#define NP 128           // 2*proj dim
#define B_DIM 8
#define S_DIM 2048
#define M_TOT (B_DIM * S_DIM)   // 16384

#define BMR 32           // rows per block
#define BK 32
#define NCH (E_DIM / BK) // 32 chunks

typedef __attribute__((ext_vector_type(8))) short short8v;  // 8 bf16 (4 VGPR)
typedef __attribute__((ext_vector_type(4))) float f32x4;    // MFMA acc / vec IO

__device__ __forceinline__ void gload16(const void* g, void* l) {
    __builtin_amdgcn_global_load_lds(
        (const __attribute__((address_space(1))) unsigned int*)g,
        (__attribute__((address_space(3))) unsigned int*)(uintptr_t)l,
        16, 0, 0);
}

// RNE two-fold split: a ~= hi + lo, residual <= 2^-18|a|.
__device__ __forceinline__ unsigned pk_rn(float a, float b) {
    float2 p; p.x = a; p.y = b;
    __hip_bfloat162 h2 = __float22bfloat162_rn(p);
    unsigned r;
    __builtin_memcpy(&r, &h2, sizeof(r));
    return r;
}

__device__ __forceinline__ void cvt_hilo(const f32x4 v0, const f32x4 v1,
                                         short8v& h, short8v& l) {
    union { unsigned u[4]; short8v s; } H, L;
    H.u[0] = pk_rn(v0.x, v0.y);
    H.u[1] = pk_rn(v0.z, v0.w);
    H.u[2] = pk_rn(v1.x, v1.y);
    H.u[3] = pk_rn(v1.z, v1.w);
    const float r0 = v0.x - __uint_as_float(H.u[0] << 16);
    const float r1 = v0.y - __uint_as_float(H.u[0] & 0xFFFF0000u);
    const float r2 = v0.z - __uint_as_float(H.u[1] << 16);
    const float r3 = v0.w - __uint_as_float(H.u[1] & 0xFFFF0000u);
    const float r4 = v1.x - __uint_as_float(H.u[2] << 16);
    const float r5 = v1.y - __uint_as_float(H.u[2] & 0xFFFF0000u);
    const float r6 = v1.z - __uint_as_float(H.u[3] << 16);
    const float r7 = v1.w - __uint_as_float(H.u[3] & 0xFFFF0000u);
    L.u[0] = pk_rn(r0, r1);
    L.u[1] = pk_rn(r2, r3);
    L.u[2] = pk_rn(r4, r5);
    L.u[3] = pk_rn(r6, r7);
    h = H.s; l = L.s;
}

// ---------------- K0: pre-convert W -> bf16 hi/lo images in staged layout ----------------
__global__ __launch_bounds__(256) void conv_w(const float* __restrict__ W,
                                              ushort* __restrict__ hiImg,
                                              ushort* __restrict__ loImg) {
    const int t = blockIdx.x * 256 + threadIdx.x;  // 16384 threads
    const int c  = t & 127;
    const int q  = (t >> 7) & 3;
    const int ch = t >> 9;
    const float* src = W + (size_t)c * E_DIM + ch * 32 + q * 8;
    const f32x4 v0 = *(const f32x4*)src;
    const f32x4 v1 = *(const f32x4*)(src + 4);
    short8v h, l;
    cvt_hilo(v0, v1, h, l);
    const size_t off = ((size_t)(ch * 4 + q) * NP + c) * 8;
    *(short8v*)&hiImg[off] = h;
    *(short8v*)&loImg[off] = l;
}

// ---------------- K1: single-pass bf16-MFMA GEMM, bias fused (r12 champion) ----------------
__global__ __launch_bounds__(256, 2) void gemm_qk(const float* __restrict__ A,
                                                  const ushort* __restrict__ hiImg,
                                                  const ushort* __restrict__ loImg,
                                                  const float* __restrict__ bias,
                                                  float* __restrict__ qk) {
    __shared__ __align__(16) float  As[3][BMR][BK];   // 12 KB
    __shared__ __align__(16) ushort Whi[3][4][NP][8]; // 24 KB
    __shared__ __align__(16) ushort Wlo[3][4][NP][8]; // 24 KB  (60 KB total)
    const int tid = threadIdx.x;
    const int m0  = blockIdx.x * BMR;
    const int w   = __builtin_amdgcn_readfirstlane(tid >> 6);  // wave id (uniform)
    const int ln  = tid & 63;
    const int lr  = ln >> 3;        // staging row in 8-row group
    const int g8  = ln & 7;         // staging slot granule
    const int row16 = ln & 15;      // frag row/col
    const int kq    = ln >> 4;      // k-quadrant
    const int r7    = row16 & 7;
    const int sg0 = ((((kq << 1) | 0) ^ r7) & 7) << 2;  // A slot offsets (floats)
    const int sg1 = ((((kq << 1) | 1) ^ r7) & 7) << 2;

    const float*  aS = A + (size_t)(m0 + w * 8 + lr) * E_DIM + ((g8 ^ lr) << 2);
    const ushort* hS = hiImg + (size_t)(w * 2) * 512 + ln * 8;
    const ushort* lS = loImg + (size_t)(w * 2) * 512 + ln * 8;

    float bias2[2];
    bias2[0] = bias[w * 32 + row16];
    bias2[1] = bias[w * 32 + 16 + row16];

    f32x4 acc[2][2];
#pragma unroll
    for (int i = 0; i < 2; ++i)
#pragma unroll
        for (int j = 0; j < 2; ++j) acc[i][j] = (f32x4){0.f, 0.f, 0.f, 0.f};

#define STAGE(BUF, CH)                                                          \
    {                                                                           \
        gload16(aS + (size_t)(CH) * BK, &As[BUF][w * 8][0]);                    \
        gload16(hS + (size_t)(CH) * 4096,       (ushort*)Whi[BUF] + (w * 2) * 512);       \
        gload16(hS + (size_t)(CH) * 4096 + 512, (ushort*)Whi[BUF] + (w * 2 + 1) * 512);   \
        gload16(lS + (size_t)(CH) * 4096,       (ushort*)Wlo[BUF] + (w * 2) * 512);       \
        gload16(lS + (size_t)(CH) * 4096 + 512, (ushort*)Wlo[BUF] + (w * 2 + 1) * 512);   \
    }

    STAGE(0, 0)
    STAGE(1, 1)

#pragma unroll
    for (int ch = 0; ch < NCH; ++ch) {
        const int buf = ch % 3;
        if (ch == NCH - 1) {
            asm volatile("s_waitcnt vmcnt(0)" ::: "memory");
        } else {
            asm volatile("s_waitcnt vmcnt(5)" ::: "memory");
        }
        __builtin_amdgcn_sched_barrier(0);
        __builtin_amdgcn_s_barrier();
        if (ch + 2 < NCH) {
            STAGE((ch + 2) % 3, ch + 2)
        }
        short8v ah[2], al[2];
#pragma unroll
        for (int fi = 0; fi < 2; ++fi) {
            const float* base = &As[buf][fi * 16 + row16][0];
            const f32x4 v0 = *(const f32x4*)(base + sg0);
            const f32x4 v1 = *(const f32x4*)(base + sg1);
            cvt_hilo(v0, v1, ah[fi], al[fi]);
        }
        short8v wh[2], wl[2];
#pragma unroll
        for (int fj = 0; fj < 2; ++fj) {
            wh[fj] = *(const short8v*)&Whi[buf][kq][w * 32 + fj * 16 + row16][0];
            wl[fj] = *(const short8v*)&Wlo[buf][kq][w * 32 + fj * 16 + row16][0];
        }
#pragma unroll
        for (int fi = 0; fi < 2; ++fi)
#pragma unroll
            for (int fj = 0; fj < 2; ++fj) {
                acc[fi][fj] = __builtin_amdgcn_mfma_f32_16x16x32_bf16(
                    ah[fi], wh[fj], acc[fi][fj], 0, 0, 0);
                acc[fi][fj] = __builtin_amdgcn_mfma_f32_16x16x32_bf16(
                    ah[fi], wl[fj], acc[fi][fj], 0, 0, 0);
                acc[fi][fj] = __builtin_amdgcn_mfma_f32_16x16x32_bf16(
                    al[fi], wh[fj], acc[fi][fj], 0, 0, 0);
            }
    }
#undef STAGE

    // C/D layout (m89): col = lane&15, row = (lane>>4)*4 + r
#pragma unroll
    for (int fi = 0; fi < 2; ++fi)
#pragma unroll
        for (int fj = 0; fj < 2; ++fj) {
#pragma unroll
            for (int r = 0; r < 4; ++r) {
                const int m = m0 + fi * 16 + kq * 4 + r;
                const int p = w * 32 + fj * 16 + row16;
                qk[(size_t)m * NP + p] = acc[fi][fj][r] + bias2[fj];
            }
        }
}

// ---------------- K2+K3 fused: scores + softmax + combine + scan, per batch ----------------
// Key fact: P1(s=0)=0 for every batch (channel-1 score is -inf at s=0), so the
// flat-roll wrap term at batch boundaries is sqrt(P0*0+1e-6) — combine is
// per-batch-local. 8 blocks (one per batch) x 1024 threads, 2 positions each.
__global__ __launch_bounds__(1024) void scores_scan(const float* __restrict__ qk,
                                                    const float* __restrict__ prior,
                                                    float* __restrict__ out_na,
                                                    float* __restrict__ cs) {
    __shared__ float shP1[S_DIM];    // 8 KB
    __shared__ float shScan[1024];   // 4 KB
    const int b = blockIdx.x;
    const int tid = threadIdx.x;

    float P0v[2], P1v[2];
#pragma unroll
    for (int u = 0; u < 2; ++u) {
        const int s = tid * 2 + u;
        float P0, P1;
        if (s == 0)              { P0 = 1.f; P1 = 0.f; }
        else if (s == S_DIM - 1) { P0 = 0.f; P1 = 1.f; }
        else {
            const int m = s * B_DIM + b;
            const f32x4* qv = (const f32x4*)(qk + (size_t)m * NP);
            const f32x4* kf = (const f32x4*)(qk + (size_t)(m + B_DIM) * NP + PD);
            const f32x4* kb = (const f32x4*)(qk + (size_t)(m - B_DIM) * NP + PD);
            float f = 0.f, g = 0.f;
#pragma unroll
            for (int i = 0; i < 16; ++i) {
                const f32x4 q4 = qv[i];
                const f32x4 f4 = kf[i];
                const f32x4 b4 = kb[i];
                f += q4.x * f4.x + q4.y * f4.y + q4.z * f4.z + q4.w * f4.w;
                g += q4.x * b4.x + q4.y * b4.y + q4.z * b4.z + q4.w * b4.w;
            }
            const float s0 = f * (1.f / (float)E_DIM);
            const float s1 = g * (1.f / (float)E_DIM);
            const float mx = fmaxf(s0, s1);
            const float e0 = __expf(s0 - mx), e1 = __expf(s1 - mx);
            const float inv = 1.f / (e0 + e1);
            P0 = e0 * inv; P1 = e1 * inv;
        }
        P0v[u] = P0; P1v[u] = P1;
        shP1[s] = P1;
    }
    __syncthreads();

    // combine (P1 of s+1; s=2047 -> next batch's s=0 -> 0) + log
    float lg[2];
#pragma unroll
    for (int u = 0; u < 2; ++u) {
        const int s = tid * 2 + u;
        const float sp = (s == S_DIM - 1) ? 0.f : shP1[s + 1];
        const float pr = prior[b * S_DIM + s];
        const float na = pr + (1.f - pr) * sqrtf(P0v[u] * sp + 1e-6f);
        out_na[b * S_DIM + s] = na;
        lg[u] = __logf(na);
    }
    const float run = lg[0] + lg[1];
    shScan[tid] = run;
    __syncthreads();
    // inclusive Hillis-Steele over 1024 thread totals
    for (int off = 1; off < 1024; off <<= 1) {
        float v = shScan[tid];
        if (tid >= off) v += shScan[tid - off];
        __syncthreads();
        shScan[tid] = v;
        __syncthreads();
    }
    const float offset = (tid > 0) ? shScan[tid - 1] : 0.f;
    cs[b * S_DIM + tid * 2]     = offset;            // exclusive prefix
    cs[b * S_DIM + tid * 2 + 1] = offset + lg[0];
}

// ---------------- K4: big output C[b,i,j] = exp(sign*(cs[j]-cs[i])), 0 on diag ----------------
__global__ __launch_bounds__(256) void big_out(const float* __restrict__ cs,
                                               float* __restrict__ out) {
    const int bi = blockIdx.x;          // b*S + i
    const int b = bi >> 11;             // / S_DIM
    const int i = bi & (S_DIM - 1);
    const float ci = cs[b * S_DIM + i];
    const float* crow = cs + (size_t)b * S_DIM;
    float* orow = out + (size_t)bi * S_DIM;
    const int j0 = threadIdx.x * 8;
#pragma unroll
    for (int h = 0; h < 2; ++h) {
        const int j = j0 + h * 4;
        const f32x4 cj = *(const f32x4*)&crow[j];
        f32x4 o;
        {
            const int jj = j + 0; const float m = (jj > i) ? (cj.x - ci) : (ci - cj.x);
            o.x = (jj == i) ? 0.f : __expf(m);
        }
        {
            const int jj = j + 1; const float m = (jj > i) ? (cj.y - ci) : (ci - cj.y);
            o.y = (jj == i) ? 0.f : __expf(m);
        }
        {
            const int jj = j + 2; const float m = (jj > i) ? (cj.z - ci) : (ci - cj.z);
            o.z = (jj == i) ? 0.f : __expf(m);
        }
        {
            const int jj = j + 3; const float m = (jj > i) ? (cj.w - ci) : (ci - cj.w);
            o.w = (jj == i) ? 0.f : __expf(m);
        }
        *(f32x4*)&orow[j] = o;
    }
}

extern "C" void kernel_launch(void* const* d_in, const int* in_sizes, int n_in,
                              void* d_out, int out_size, void* d_ws, size_t ws_size,
                              hipStream_t stream) {
    const float* context = (const float*)d_in[0];   // (S,B,E) fp32
    const float* prior   = (const float*)d_in[1];   // (B,S) fp32
    const float* W       = (const float*)d_in[2];   // (128,1024) fp32
    const float* bias    = (const float*)d_in[3];   // (128,) fp32
    float* out = (float*)d_out;

    float* qk = (float*)d_ws;                          // 16384*128 floats (8 MB)
    float* cs = qk + (size_t)M_TOT * NP;               // 16384 floats
    // W bf16 hi/lo images (256 KB each) live in d_out's C-region; conv_w writes,
    // gemm reads, big_out overwrites afterwards (stream-ordered, safe)
    ushort* hiImg = (ushort*)out;                      // 128K ushorts
    ushort* loImg = hiImg + (size_t)NP * E_DIM;        // 128K ushorts
    float* na_out = out + (size_t)B_DIM * S_DIM * S_DIM;  // second output

    conv_w<<<64, 256, 0, stream>>>(W, hiImg, loImg);
    gemm_qk<<<M_TOT / BMR, 256, 0, stream>>>(context, hiImg, loImg, bias, qk);
    scores_scan<<<B_DIM, 1024, 0, stream>>>(qk, prior, na_out, cs);
    big_out<<<M_TOT, 256, 0, stream>>>(cs, out);
}